// Round 15
// baseline (2214.371 us; speedup 1.0000x reference)
//
#include <hip/hip_runtime.h>
#include <cstdint>
#include <cstddef>

// Problem constants
#define B_    16
#define T_    32
#define H_    512
#define P_    1024        // 32*32 spatial
#define NPOS  16384       // B_*P_
#define NG    2048        // 4*H_

#define LOG2E   1.442695041f
#define LOG2E2  2.885390082f

typedef __attribute__((ext_vector_type(8))) short short8;
typedef __attribute__((ext_vector_type(4))) float f32x4;

__device__ __forceinline__ unsigned short f2bf(float f) {
  uint32_t u = __float_as_uint(f);
  u += 0x7fffu + ((u >> 16) & 1u);     // RNE
  return (unsigned short)(u >> 16);
}
__device__ __forceinline__ float bflo(uint32_t u) { return __uint_as_float(u << 16); }
__device__ __forceinline__ float bfhi(uint32_t u) { return __uint_as_float(u & 0xffff0000u); }

// gates pre-scaled by log2e (2*log2e for g-gate) at repack: bare exp2 + rcp.
__device__ __forceinline__ float sig2(float y) {          // sigmoid(x), y = x*log2e
  return __builtin_amdgcn_rcpf(1.0f + exp2f(-y));
}
__device__ __forceinline__ float th2(float y) {           // tanh(x), y = 2x*log2e
  return 1.0f - 2.0f * __builtin_amdgcn_rcpf(exp2f(y) + 1.0f);
}

__device__ __forceinline__ void gload_lds16(const void* g, void* l) {
  __builtin_amdgcn_global_load_lds(
      (const __attribute__((address_space(1))) void*)g,
      (__attribute__((address_space(3))) void*)l, 16, 0, 0);
}

// ---------------- repack kernels ----------------
// Wp[r][k] = bf16(s_g * Wc[o][1+k]),  r = ch*4+g,  o = g*512+ch.
// s_g = log2e for i,f,o (sigmoid inputs), 2*log2e for g (tanh input) --
// folds the exp->exp2 conversion multiplies into the weights (exact modulo
// bf16 rounding of the scaled value).
__global__ void repack_w(const float* __restrict__ Wc, const float* __restrict__ bconv,
                         unsigned short* __restrict__ Wp, float* __restrict__ w0x,
                         float* __restrict__ bx) {
  int idx = blockIdx.x * 256 + threadIdx.x;       // 2048*512 exact
  int r = idx >> 9, k = idx & 511;
  int ch = r >> 2, g = r & 3;
  int o = g * 512 + ch;
  float s = (g == 3) ? LOG2E2 : LOG2E;
  Wp[idx] = f2bf(Wc[o * 513 + 1 + k] * s);
  if (k == 0) { w0x[r] = Wc[o * 513] * s; bx[r] = bconv[o] * s; }
}

// wppb: split-bf16 W_post table for the fused u-GEMM (NOT scaled -- linear).
__global__ void repack_wpost(const float* __restrict__ Wpost, unsigned short* __restrict__ wppb) {
  int idx = blockIdx.x * 256 + threadIdx.x;       // 16*512 = 8192 exact
  if (idx >= 16 * 512) return;
  int j = idx >> 9, c = idx & 511;
  float v = (j < 9) ? Wpost[c * 9 + j] : 0.f;
  unsigned short hi = f2bf(v);
  float lo = v - bflo((uint32_t)hi);
  wppb[idx] = hi;
  wppb[16 * 512 + idx] = f2bf(lo);
}

// ---------------- fused gates-GEMM + LSTM pointwise + u-GEMM + stencil ----------------
// R14 base (verified: 53.5 us avg, total 1761) with two independent micro-cuts:
//  (1) T3-minimum 2-phase double-buffer at BK=32 (guide 5.5 recipe): LDS still
//      48 KB (2x16KB A + 2x8KB B), 2 blocks/CU unchanged; stage(k+1 -> buf^1)
//      issued BEFORE compute(buf); one barrier/chunk. Uses R6's verified
//      64B-row chunk-XOR layout (conflicts 327K).
//  (2) exp2 weight-folding: sigmoid/tanh = bare exp2+rcp (scales folded at
//      repack) -- removes ~128 v_mul/thread from the epilogue.
// Everything else verbatim from R14: T1 XCD swizzle (FETCH 76->33MB), stash
// XOR-swizzle, scattered 2-byte Cst RMW, phase-2 u-GEMM + same-XCD atomics,
// triple-buffered u, fused 9-load stencil.
__global__ __launch_bounds__(256, 2)
void lstm_step(const unsigned short* __restrict__ Wp,
               const unsigned short* __restrict__ hprev,
               unsigned short* __restrict__ hnext,
               _Float16* __restrict__ Cst,
               const float* __restrict__ w0x, const float* __restrict__ bxv,
               const float* __restrict__ xin,
               const unsigned short* __restrict__ wppb,
               const float* __restrict__ uPrev, float* __restrict__ uCur,
               float* __restrict__ uNext,
               const float* __restrict__ bpost, float* __restrict__ out, int t) {
  __shared__ unsigned short As2[2][256 * 32];   // W tile dbuf, 64B rows, XOR slots (2x16 KB)
  __shared__ unsigned short Bs2[2][128 * 32];   // h tile dbuf, 64B rows, XOR slots (2x8 KB)

  const int tid = threadIdx.x;
  const int lane = tid & 63;
  const int wv = tid >> 6;
  const int wm = wv >> 1, wn = wv & 1;      // 2x2 waves over 256x128 tile
  const int q = lane >> 4, l = lane & 15;

  // T1 XCD swizzle: each XCD owns 16 contiguous pos-tiles x all 8 row-tiles.
  const int lid = blockIdx.x;               // 0..1023
  const int xcd = lid & 7;
  const int s   = lid >> 3;                 // 0..127
  const int ny  = xcd * 16 + (s & 15);      // pos-tile 0..127
  const int rx  = s >> 4;                   // row-tile 0..7
  const int r0  = rx * 256;                 // gate-row base
  const int n0  = ny * 128;                 // position base
  const int ch0 = rx * 64;

  // staging map (R6-verified): LDS byte j*4096 + tid*16 -> row j*64 + (tid>>2),
  // slot tid&3; slot holds global chunk (tid&3)^((tid>>3)&3) (pre-swizzled
  // source, linear DMA dest -- rule #21).
  const int srow = tid >> 2;                // 0..63
  const int gchunk = (tid & 3) ^ ((tid >> 3) & 3);
  const unsigned short* gA = Wp    + (size_t)(r0 + srow) * 512 + gchunk * 8;
  const unsigned short* gB = hprev + (size_t)(n0 + srow) * 512 + gchunk * 8;

  // stage K-chunk kt2 (32 wide) into buffer bb: 6 gloads/thread
  auto stage = [&](int bb, int kt2) {
    int kc = kt2 * 32;
    char* lA = (char*)As2[bb] + wv * 1024;
    char* lB = (char*)Bs2[bb] + wv * 1024;
#pragma unroll
    for (int j = 0; j < 4; ++j)
      gload_lds16(gA + (size_t)(j * 64) * 512 + kc, lA + j * 4096);
#pragma unroll
    for (int j = 0; j < 2; ++j)
      gload_lds16(gB + (size_t)(j * 64) * 512 + kc, lB + j * 4096);
  };

  f32x4 acc[8][4] = {};

  stage(0, 0);                              // chunk 0 in flight

  // fused 3x3 stencil for step t-1 (R6-verified-free 9-load form),
  // overlapped with chunk-0 staging latency
  if (t > 0 && tid < 16) {
    int pix = lid * 16 + tid;               // 1024*16 = 16384 exact
    int b = pix >> 10, p = pix & 1023;
    int py = p >> 5, px = p & 31;
    float a = bpost[0];
#pragma unroll
    for (int dy = -1; dy <= 1; ++dy) {
      int nyy = py + dy;
      if ((unsigned)nyy > 31u) continue;
#pragma unroll
      for (int dx = -1; dx <= 1; ++dx) {
        int nx = px + dx;
        if ((unsigned)nx > 31u) continue;
        int j = (dy + 1) * 3 + (dx + 1);
        a += uPrev[j * NPOS + (b << 10) + (nyy << 5) + nx];
      }
    }
    out[((b * T_ + (t - 1)) << 10) + p] = a;
  }
  // zero u[(t+1)%3] for the NEXT step's accumulation (9*NPOS = 1024*144)
  if (tid >= 16 && tid < 160)
    uNext[lid * 144 + (tid - 16)] = 0.f;

  __syncthreads();                          // drains vmcnt: buffer 0 ready

  // fragment slot offset (shorts): global chunk q stored at q ^ ((row>>1)&3);
  // rows are base+l with base%16==0 -> key = (l>>1)&3, lane-constant.
  const int cxs = (q ^ ((l >> 1) & 3)) << 3;

  for (int kt = 0; kt < 16; ++kt) {
    const int cur = kt & 1;
    if (kt < 15) stage(cur ^ 1, kt + 1);    // prefetch next chunk into other buffer

    const unsigned short* Ab = As2[cur];
    const unsigned short* Bb = Bs2[cur];
    short8 af[8], bf_[4];
#pragma unroll
    for (int mi = 0; mi < 8; ++mi) {
      int row = wm * 128 + mi * 16 + l;
      af[mi] = *(const short8*)(Ab + row * 32 + cxs);
    }
#pragma unroll
    for (int ni = 0; ni < 4; ++ni) {
      int row = wn * 64 + ni * 16 + l;
      bf_[ni] = *(const short8*)(Bb + row * 32 + cxs);
    }
#pragma unroll
    for (int mi = 0; mi < 8; ++mi)
#pragma unroll
      for (int ni = 0; ni < 4; ++ni)
        acc[mi][ni] = __builtin_amdgcn_mfma_f32_16x16x32_bf16(af[mi], bf_[ni], acc[mi][ni], 0, 0, 0);

    __syncthreads();   // one barrier/chunk: reads done + next buffer's DMA drained
  }

  // ---- epilogue: lane's 4 regs of acc[mi][ni] = (i,f,o,g) for one (ch,pos) ----
  float xv[4]; int posL[4]; size_t cbase[4];
#pragma unroll
  for (int ni = 0; ni < 4; ++ni) {
    posL[ni] = wn * 64 + ni * 16 + l;
    int pos = n0 + posL[ni];
    int b = pos >> 10, p = pos & 1023;
    xv[ni] = xin[((b * T_ + t) << 10) + p];
    cbase[ni] = ((size_t)b << 19) + p;    // b*512*1024 + p
  }
  unsigned short* stash = (unsigned short*)As2[0];   // 16 KB, loop done -> free
#pragma unroll
  for (int mi = 0; mi < 8; ++mi) {
    int chl = wm * 32 + mi * 4 + q;                    // local ch 0..63
    int rg = r0 + wm * 128 + mi * 16 + q * 4;          // global row of reg0
    float4 w0 = *(const float4*)(w0x + rg);
    float4 bb = *(const float4*)(bxv + rg);
    int ch = ch0 + chl;
#pragma unroll
    for (int ni = 0; ni < 4; ++ni) {
      f32x4 g = acc[mi][ni];
      float gi = g[0] + w0.x * xv[ni] + bb.x;          // pre-scaled by log2e
      float gf = g[1] + w0.y * xv[ni] + bb.y;
      float go = g[2] + w0.z * xv[ni] + bb.z;
      float gg = g[3] + w0.w * xv[ni] + bb.w;          // pre-scaled by 2*log2e
      size_t cidx = cbase[ni] + ((size_t)ch << 10);
      float cold = (float)Cst[cidx];
      float cn = sig2(gf) * cold + sig2(gi) + th2(gg);
      float hn = sig2(go) + th2(cn * LOG2E2);
      Cst[cidx] = (_Float16)cn;
      // stash for coalesced store, chunk-XOR swizzled (verified 327K conflicts)
      stash[posL[ni] * 64 + (chl ^ ((posL[ni] & 7) << 3))] = f2bf(hn);
    }
  }
  __syncthreads();

  // h store (reads stash)
  {
    int pl = tid >> 1;                 // 0..127 local pos
    int cb2 = (tid & 1) << 2;          // chunk base: 0 or 4 (8-short chunks)
    const unsigned short* srcrow = stash + pl * 64;
    unsigned short* dst = hnext + (size_t)(n0 + pl) * 512 + ch0 + (cb2 << 3);
#pragma unroll
    for (int i = 0; i < 4; ++i)
      ((uint4*)dst)[i] = *(const uint4*)(srcrow + (((cb2 + i) ^ (pl & 7)) << 3));
  }

  // ---- phase-2: uCur[j][pix] += sum_{ch in block} wpp[j][ch] * h[pos][ch] ----
  // 16x128x64 GEMM on the stash (8 MFMAs, split-bf16). The 8 rx-blocks of a
  // pixel accumulate via HW f32 atomicAdd -- same-XCD under T1, L2-resident.
  {
    const unsigned short* wb_hi = wppb;               // [16][512]
    const unsigned short* wb_lo = wppb + 16 * 512;
    const int posg = wv * 32;                         // wave's 32 positions
    f32x4 a2[2] = {};
#pragma unroll
    for (int kk = 0; kk < 2; ++kk) {
      const int wo = l * 512 + ch0 + kk * 32 + q * 8;
      short8 whi = *(const short8*)(wb_hi + wo);
      short8 wlo = *(const short8*)(wb_lo + wo);
#pragma unroll
      for (int ni2 = 0; ni2 < 2; ++ni2) {
        int row = posg + ni2 * 16 + l;
        int sidx = row * 64 + (((kk * 4 + q) ^ (row & 7)) * 8);
        short8 hf = *(const short8*)(stash + sidx);
        a2[ni2] = __builtin_amdgcn_mfma_f32_16x16x32_bf16(whi, hf, a2[ni2], 0, 0, 0);
        a2[ni2] = __builtin_amdgcn_mfma_f32_16x16x32_bf16(wlo, hf, a2[ni2], 0, 0, 0);
      }
    }
#pragma unroll
    for (int ni2 = 0; ni2 < 2; ++ni2) {
      int pix = n0 + posg + ni2 * 16 + l;
#pragma unroll
      for (int r = 0; r < 4; ++r) {
        int j = q * 4 + r;
        if (j < 9)
          unsafeAtomicAdd(&uCur[j * NPOS + pix], a2[ni2][r]);
      }
    }
  }
}

// ---------------- 3x3 stencil over u (tail, t=T-1 only) ----------------
__global__ __launch_bounds__(256)
void conv_st(const float* __restrict__ u, const float* __restrict__ bpost,
             float* __restrict__ out, int t) {
  int idx = blockIdx.x * 256 + threadIdx.x;        // 0..16383
  int b = idx >> 10, p = idx & 1023;
  int py = p >> 5, px = p & 31;
  float acc = bpost[0];
#pragma unroll
  for (int dy = -1; dy <= 1; ++dy) {
    int ny = py + dy;
    if ((unsigned)ny > 31u) continue;
#pragma unroll
    for (int dx = -1; dx <= 1; ++dx) {
      int nx = px + dx;
      if ((unsigned)nx > 31u) continue;
      int j = (dy + 1) * 3 + (dx + 1);
      acc += u[j * NPOS + (b << 10) + (ny << 5) + nx];
    }
  }
  out[((b * T_ + t) << 10) + p] = acc;
}

// ---------------- launch ----------------
extern "C" void kernel_launch(void* const* d_in, const int* in_sizes, int n_in,
                              void* d_out, int out_size, void* d_ws, size_t ws_size,
                              hipStream_t stream) {
  const float* x     = (const float*)d_in[0];
  const float* Wconv = (const float*)d_in[1];
  const float* bconv = (const float*)d_in[2];
  const float* Wpost = (const float*)d_in[3];
  const float* bpost = (const float*)d_in[4];
  float* out = (float*)d_out;
  char* ws = (char*)d_ws;

  // workspace layout (bytes)
  unsigned short* h0   = (unsigned short*)(ws);                 // 16 MB
  unsigned short* h1   = (unsigned short*)(ws + 16777216);      // 16 MB
  _Float16*       Cst  = (_Float16*)(ws + 33554432);            // 16 MB (fp16 state)
  unsigned short* Wp   = (unsigned short*)(ws + 50331648);      // 2 MB
  float*          w0x  = (float*)(ws + 52428800);               // 8 KB
  float*          bx   = (float*)(ws + 52436992);               // 8 KB
  unsigned short* wppb = (unsigned short*)(ws + 52445184);      // 32 KB (split-bf16 W_post)
  float*          u0   = (float*)(ws + 52477952);               // 576 KB (9*16384 f32)
  float*          u1   = (float*)(ws + 53067776);               // 576 KB
  float*          u2   = (float*)(ws + 53657600);               // 576 KB
  float* ub[3] = {u0, u1, u2};

  hipMemsetAsync(h0, 0, 16777216, stream);
  hipMemsetAsync(Cst, 0, 16777216, stream);
  hipMemsetAsync(u0, 0, 589824, stream);
  repack_w<<<4096, 256, 0, stream>>>(Wconv, bconv, Wp, w0x, bx);
  repack_wpost<<<32, 256, 0, stream>>>(Wpost, wppb);

  unsigned short* hp = h0;
  unsigned short* hn = h1;
  for (int t = 0; t < T_; ++t) {
    const float* uPrev = ub[(t + 2) % 3];   // written by step t-1
    float*       uCur  = ub[t % 3];         // accumulated this step (pre-zeroed)
    float*       uNext = ub[(t + 1) % 3];   // zeroed this step for step t+1
    lstm_step<<<1024, 256, 0, stream>>>(Wp, hp, hn, Cst, w0x, bx, x, wppb,
                                        uPrev, uCur, uNext, bpost, out, t);
    unsigned short* tmp = hp; hp = hn; hn = tmp;
  }
  conv_st<<<64, 256, 0, stream>>>(ub[(T_ - 1) % 3], bpost, out, T_ - 1);
}

// Round 17
// 1834.259 us; speedup vs baseline: 1.2072x; 1.2072x over previous
//
#include <hip/hip_runtime.h>
#include <cstdint>
#include <cstddef>

// Problem constants
#define B_    16
#define T_    32
#define H_    512
#define P_    1024        // 32*32 spatial
#define NPOS  16384       // B_*P_
#define NG    2048        // 4*H_

#define LOG2E   1.442695041f
#define LOG2E2  2.885390082f

typedef __attribute__((ext_vector_type(8))) short short8;
typedef __attribute__((ext_vector_type(4))) float f32x4;
typedef _Float16 f16x4 __attribute__((ext_vector_type(4)));

__device__ __forceinline__ unsigned short f2bf(float f) {
  uint32_t u = __float_as_uint(f);
  u += 0x7fffu + ((u >> 16) & 1u);     // RNE
  return (unsigned short)(u >> 16);
}
__device__ __forceinline__ float bflo(uint32_t u) { return __uint_as_float(u << 16); }
__device__ __forceinline__ float bfhi(uint32_t u) { return __uint_as_float(u & 0xffff0000u); }

// gates pre-scaled by log2e (2*log2e for g-gate) at repack: bare exp2 + rcp.
__device__ __forceinline__ float sig2(float y) {          // sigmoid(x), y = x*log2e
  return __builtin_amdgcn_rcpf(1.0f + exp2f(-y));
}
__device__ __forceinline__ float th2(float y) {           // tanh(x), y = 2x*log2e
  return 1.0f - 2.0f * __builtin_amdgcn_rcpf(exp2f(y) + 1.0f);
}

__device__ __forceinline__ void gload_lds16(const void* g, void* l) {
  __builtin_amdgcn_global_load_lds(
      (const __attribute__((address_space(1))) void*)g,
      (__attribute__((address_space(3))) void*)l, 16, 0, 0);
}

// ---------------- repack kernels ----------------
// Wp[r][k] = bf16(s_g * Wc[o][1+k]),  r = ch*4+g,  o = g*512+ch.
// s_g = log2e for i,f,o (sigmoid inputs), 2*log2e for g (tanh input).
__global__ void repack_w(const float* __restrict__ Wc, const float* __restrict__ bconv,
                         unsigned short* __restrict__ Wp, float* __restrict__ w0x,
                         float* __restrict__ bx) {
  int idx = blockIdx.x * 256 + threadIdx.x;       // 2048*512 exact
  int r = idx >> 9, k = idx & 511;
  int ch = r >> 2, g = r & 3;
  int o = g * 512 + ch;
  float s = (g == 3) ? LOG2E2 : LOG2E;
  Wp[idx] = f2bf(Wc[o * 513 + 1 + k] * s);
  if (k == 0) { w0x[r] = Wc[o * 513] * s; bx[r] = bconv[o] * s; }
}

// wppb: split-bf16 W_post table for the fused u-GEMM (NOT scaled -- linear).
__global__ void repack_wpost(const float* __restrict__ Wpost, unsigned short* __restrict__ wppb) {
  int idx = blockIdx.x * 256 + threadIdx.x;       // 16*512 = 8192 exact
  if (idx >= 16 * 512) return;
  int j = idx >> 9, c = idx & 511;
  float v = (j < 9) ? Wpost[c * 9 + j] : 0.f;
  unsigned short hi = f2bf(v);
  float lo = v - bflo((uint32_t)hi);
  wppb[idx] = hi;
  wppb[16 * 512 + idx] = f2bf(lo);
}

// ---------------- fused gates-GEMM + LSTM pointwise + u-GEMM + stencil ----------------
// R14-exact structure (verified 1761 us total): BK=64 single-buffer 48 KB,
// 8 chunks/step (R15's BK=32 dbuf = 16 vmcnt(0) drains -> 75 us, reverted),
// 2x2 waves over 256x128, T1 XCD swizzle, stash XOR-swizzle, phase-2 u-GEMM
// with same-XCD atomics, triple-buffered u, fused 9-load stencil.
// Two epilogue-only cuts vs R14:
//  (1) exp2 weight-folding (scales folded at repack; bare exp2+rcp).
//  (2) Cst relabeled to fragment-order with LANE-FASTEST axis:
//      idx = (((lid*4+wv)*8+mi)*64+lane)*4+ni -> per mi one 8B f16x4
//      load+store per lane, wave = single 512B segment. Replaces 32 scattered
//      2-byte RMWs (R10's failed version had 64B lane stride; this is 8B).
// [Resubmitted verbatim: round-16 bench was a container-acquire infra failure,
//  same generic error as rounds 8/11, both of which passed on resubmission.]
__global__ __launch_bounds__(256, 2)
void lstm_step(const unsigned short* __restrict__ Wp,
               const unsigned short* __restrict__ hprev,
               unsigned short* __restrict__ hnext,
               _Float16* __restrict__ Cst,
               const float* __restrict__ w0x, const float* __restrict__ bxv,
               const float* __restrict__ xin,
               const unsigned short* __restrict__ wppb,
               const float* __restrict__ uPrev, float* __restrict__ uCur,
               float* __restrict__ uNext,
               const float* __restrict__ bpost, float* __restrict__ out, int t) {
  __shared__ unsigned short As[256 * 64];   // W tile   [row r][k], XOR-swizzled chunks (32 KB)
  __shared__ unsigned short Bs[128 * 64];   // h tile   [pos][k],   XOR-swizzled chunks (16 KB)

  const int tid = threadIdx.x;
  const int lane = tid & 63;
  const int wv = tid >> 6;
  const int wm = wv >> 1, wn = wv & 1;      // 2x2 waves over 256x128 tile
  const int q = lane >> 4, l = lane & 15;

  // T1 XCD swizzle: each XCD owns 16 contiguous pos-tiles x all 8 row-tiles.
  const int lid = blockIdx.x;               // 0..1023
  const int xcd = lid & 7;
  const int s   = lid >> 3;                 // 0..127
  const int ny  = xcd * 16 + (s & 15);      // pos-tile 0..127
  const int rx  = s >> 4;                   // row-tile 0..7
  const int r0  = rx * 256;                 // gate-row base
  const int n0  = ny * 128;                 // position base
  const int ch0 = rx * 64;

  // staging map: lds byte j*4096 + tid*16 -> row j*32 + (tid>>3), stored chunk tid&7
  const int srow = tid >> 3;
  const int lchunk = (tid & 7) ^ (srow & 7);
  const unsigned short* gA = Wp    + (size_t)(r0 + srow) * 512 + lchunk * 8;
  const unsigned short* gB = hprev + (size_t)(n0 + srow) * 512 + lchunk * 8;
  char* lA = (char*)As + wv * 1024;
  char* lB = (char*)Bs + wv * 1024;

  f32x4 acc[8][4] = {};

  // issue chunk-0 staging first, then overlap stencil + u-zeroing with its latency
#pragma unroll
  for (int j = 0; j < 8; ++j)
    gload_lds16(gA + (size_t)j * (32 * 512), lA + j * 4096);
#pragma unroll
  for (int j = 0; j < 4; ++j)
    gload_lds16(gB + (size_t)j * (32 * 512), lB + j * 4096);

  // fused 3x3 stencil for step t-1 (verified-free 9-load form)
  if (t > 0 && tid < 16) {
    int pix = lid * 16 + tid;               // 1024*16 = 16384 exact
    int b = pix >> 10, p = pix & 1023;
    int py = p >> 5, px = p & 31;
    float a = bpost[0];
#pragma unroll
    for (int dy = -1; dy <= 1; ++dy) {
      int nyy = py + dy;
      if ((unsigned)nyy > 31u) continue;
#pragma unroll
      for (int dx = -1; dx <= 1; ++dx) {
        int nx = px + dx;
        if ((unsigned)nx > 31u) continue;
        int j = (dy + 1) * 3 + (dx + 1);
        a += uPrev[j * NPOS + (b << 10) + (nyy << 5) + nx];
      }
    }
    out[((b * T_ + (t - 1)) << 10) + p] = a;
  }
  // zero u[(t+1)%3] for the NEXT step's accumulation (9*NPOS = 1024*144)
  if (tid >= 16 && tid < 160)
    uNext[lid * 144 + (tid - 16)] = 0.f;

  for (int kc = 0; kc < 512; kc += 64) {
    __syncthreads();                        // implicit vmcnt drain: chunk kc ready

#pragma unroll
    for (int kk = 0; kk < 2; ++kk) {
      short8 af[8], bf_[4];
#pragma unroll
      for (int mi = 0; mi < 8; ++mi) {
        int row = wm * 128 + mi * 16 + l;
        int sidx = row * 64 + (((kk * 4 + q) ^ (row & 7)) * 8);
        af[mi] = *(const short8*)(As + sidx);
      }
#pragma unroll
      for (int ni = 0; ni < 4; ++ni) {
        int row = wn * 64 + ni * 16 + l;
        int sidx = row * 64 + (((kk * 4 + q) ^ (row & 7)) * 8);
        bf_[ni] = *(const short8*)(Bs + sidx);
      }
#pragma unroll
      for (int mi = 0; mi < 8; ++mi)
#pragma unroll
        for (int ni = 0; ni < 4; ++ni)
          acc[mi][ni] = __builtin_amdgcn_mfma_f32_16x16x32_bf16(af[mi], bf_[ni], acc[mi][ni], 0, 0, 0);
    }
    __syncthreads();                        // reads done -> safe to overwrite

    if (kc < 448) {
      int kn = kc + 64;
#pragma unroll
      for (int j = 0; j < 8; ++j)
        gload_lds16(gA + (size_t)j * (32 * 512) + kn, lA + j * 4096);
#pragma unroll
      for (int j = 0; j < 4; ++j)
        gload_lds16(gB + (size_t)j * (32 * 512) + kn, lB + j * 4096);
    }
  }

  // ---- epilogue: lane's 4 regs of acc[mi][ni] = (i,f,o,g) for one (ch,pos) ----
  float xv[4]; int posL[4];
#pragma unroll
  for (int ni = 0; ni < 4; ++ni) {
    posL[ni] = wn * 64 + ni * 16 + l;
    int pos = n0 + posL[ni];
    int b = pos >> 10, p = pos & 1023;
    xv[ni] = xin[((b * T_ + t) << 10) + p];
  }
  // C state: fragment-order, lane-fastest (8B/lane contiguous, 512B/wave/mi)
  const size_t cB = ((size_t)(lid * 4 + wv) * 2048) + lane * 4;
#pragma unroll
  for (int mi = 0; mi < 8; ++mi) {
    int chl = wm * 32 + mi * 4 + q;                    // local ch 0..63
    int rg = r0 + wm * 128 + mi * 16 + q * 4;          // global row of reg0
    float4 w0 = *(const float4*)(w0x + rg);
    float4 bb = *(const float4*)(bxv + rg);
    f16x4 cv = *(const f16x4*)(Cst + cB + mi * 256);
#pragma unroll
    for (int ni = 0; ni < 4; ++ni) {
      f32x4 g = acc[mi][ni];
      float gi = g[0] + w0.x * xv[ni] + bb.x;          // pre-scaled by log2e
      float gf = g[1] + w0.y * xv[ni] + bb.y;
      float go = g[2] + w0.z * xv[ni] + bb.z;
      float gg = g[3] + w0.w * xv[ni] + bb.w;          // pre-scaled by 2*log2e
      float cold = (float)cv[ni];
      float cn = sig2(gf) * cold + sig2(gi) + th2(gg);
      float hn = sig2(go) + th2(cn * LOG2E2);
      cv[ni] = (_Float16)cn;
      // stash for coalesced store, chunk-XOR swizzled (verified 327K conflicts)
      As[posL[ni] * 64 + (chl ^ ((posL[ni] & 7) << 3))] = f2bf(hn);
    }
    *(f16x4*)(Cst + cB + mi * 256) = cv;
  }
  __syncthreads();

  // h store (reads stash)
  {
    int pl = tid >> 1;                 // 0..127 local pos
    int cb2 = (tid & 1) << 2;          // chunk base: 0 or 4 (8-short chunks)
    const unsigned short* srcrow = As + pl * 64;
    unsigned short* dst = hnext + (size_t)(n0 + pl) * 512 + ch0 + (cb2 << 3);
#pragma unroll
    for (int i = 0; i < 4; ++i)
      ((uint4*)dst)[i] = *(const uint4*)(srcrow + (((cb2 + i) ^ (pl & 7)) << 3));
  }

  // ---- phase-2: uCur[j][pix] += sum_{ch in block} wpp[j][ch] * h[pos][ch] ----
  // 16x128x64 GEMM on the stash (8 MFMAs, split-bf16). The 8 rx-blocks of a
  // pixel accumulate via HW f32 atomicAdd -- same-XCD under T1, L2-resident.
  {
    const unsigned short* wb_hi = wppb;               // [16][512]
    const unsigned short* wb_lo = wppb + 16 * 512;
    const int posg = wv * 32;                         // wave's 32 positions
    f32x4 a2[2] = {};
#pragma unroll
    for (int kk = 0; kk < 2; ++kk) {
      const int wo = l * 512 + ch0 + kk * 32 + q * 8;
      short8 whi = *(const short8*)(wb_hi + wo);
      short8 wlo = *(const short8*)(wb_lo + wo);
#pragma unroll
      for (int ni2 = 0; ni2 < 2; ++ni2) {
        int row = posg + ni2 * 16 + l;
        int sidx = row * 64 + (((kk * 4 + q) ^ (row & 7)) * 8);
        short8 hf = *(const short8*)(As + sidx);
        a2[ni2] = __builtin_amdgcn_mfma_f32_16x16x32_bf16(whi, hf, a2[ni2], 0, 0, 0);
        a2[ni2] = __builtin_amdgcn_mfma_f32_16x16x32_bf16(wlo, hf, a2[ni2], 0, 0, 0);
      }
    }
#pragma unroll
    for (int ni2 = 0; ni2 < 2; ++ni2) {
      int pix = n0 + posg + ni2 * 16 + l;
#pragma unroll
      for (int r = 0; r < 4; ++r) {
        int j = q * 4 + r;
        if (j < 9)
          unsafeAtomicAdd(&uCur[j * NPOS + pix], a2[ni2][r]);
      }
    }
  }
}

// ---------------- 3x3 stencil over u (tail, t=T-1 only) ----------------
__global__ __launch_bounds__(256)
void conv_st(const float* __restrict__ u, const float* __restrict__ bpost,
             float* __restrict__ out, int t) {
  int idx = blockIdx.x * 256 + threadIdx.x;        // 0..16383
  int b = idx >> 10, p = idx & 1023;
  int py = p >> 5, px = p & 31;
  float acc = bpost[0];
#pragma unroll
  for (int dy = -1; dy <= 1; ++dy) {
    int ny = py + dy;
    if ((unsigned)ny > 31u) continue;
#pragma unroll
    for (int dx = -1; dx <= 1; ++dx) {
      int nx = px + dx;
      if ((unsigned)nx > 31u) continue;
      int j = (dy + 1) * 3 + (dx + 1);
      acc += u[j * NPOS + (b << 10) + (ny << 5) + nx];
    }
  }
  out[((b * T_ + t) << 10) + p] = acc;
}

// ---------------- launch ----------------
extern "C" void kernel_launch(void* const* d_in, const int* in_sizes, int n_in,
                              void* d_out, int out_size, void* d_ws, size_t ws_size,
                              hipStream_t stream) {
  const float* x     = (const float*)d_in[0];
  const float* Wconv = (const float*)d_in[1];
  const float* bconv = (const float*)d_in[2];
  const float* Wpost = (const float*)d_in[3];
  const float* bpost = (const float*)d_in[4];
  float* out = (float*)d_out;
  char* ws = (char*)d_ws;

  // workspace layout (bytes)
  unsigned short* h0   = (unsigned short*)(ws);                 // 16 MB
  unsigned short* h1   = (unsigned short*)(ws + 16777216);      // 16 MB
  _Float16*       Cst  = (_Float16*)(ws + 33554432);            // 16 MB (fp16 state, fragment-order)
  unsigned short* Wp   = (unsigned short*)(ws + 50331648);      // 2 MB
  float*          w0x  = (float*)(ws + 52428800);               // 8 KB
  float*          bx   = (float*)(ws + 52436992);               // 8 KB
  unsigned short* wppb = (unsigned short*)(ws + 52445184);      // 32 KB (split-bf16 W_post)
  float*          u0   = (float*)(ws + 52477952);               // 576 KB (9*16384 f32)
  float*          u1   = (float*)(ws + 53067776);               // 576 KB
  float*          u2   = (float*)(ws + 53657600);               // 576 KB
  float* ub[3] = {u0, u1, u2};

  hipMemsetAsync(h0, 0, 16777216, stream);
  hipMemsetAsync(Cst, 0, 16777216, stream);
  hipMemsetAsync(u0, 0, 589824, stream);
  repack_w<<<4096, 256, 0, stream>>>(Wconv, bconv, Wp, w0x, bx);
  repack_wpost<<<32, 256, 0, stream>>>(Wpost, wppb);

  unsigned short* hp = h0;
  unsigned short* hn = h1;
  for (int t = 0; t < T_; ++t) {
    const float* uPrev = ub[(t + 2) % 3];   // written by step t-1
    float*       uCur  = ub[t % 3];         // accumulated this step (pre-zeroed)
    float*       uNext = ub[(t + 1) % 3];   // zeroed this step for step t+1
    lstm_step<<<1024, 256, 0, stream>>>(Wp, hp, hn, Cst, w0x, bx, x, wppb,
                                        uPrev, uCur, uNext, bpost, out, t);
    unsigned short* tmp = hp; hp = hn; hn = tmp;
  }
  conv_st<<<64, 256, 0, stream>>>(ub[(T_ - 1) % 3], bpost, out, T_ - 1);
}

// Round 18
// 1811.629 us; speedup vs baseline: 1.2223x; 1.0125x over previous
//
#include <hip/hip_runtime.h>
#include <cstdint>
#include <cstddef>

// Problem constants
#define B_    16
#define T_    32
#define H_    512
#define P_    1024        // 32*32 spatial
#define NPOS  16384       // B_*P_
#define NG    2048        // 4*H_

#define LOG2E   1.442695041f
#define LOG2E2  2.885390082f

typedef __attribute__((ext_vector_type(8))) short short8;
typedef __attribute__((ext_vector_type(4))) float f32x4;
typedef _Float16 f16x4 __attribute__((ext_vector_type(4)));

__device__ __forceinline__ unsigned short f2bf(float f) {
  uint32_t u = __float_as_uint(f);
  u += 0x7fffu + ((u >> 16) & 1u);     // RNE
  return (unsigned short)(u >> 16);
}
__device__ __forceinline__ float bflo(uint32_t u) { return __uint_as_float(u << 16); }
__device__ __forceinline__ float bfhi(uint32_t u) { return __uint_as_float(u & 0xffff0000u); }

// gates pre-scaled by log2e (2*log2e for g-gate) at repack: bare exp2 + rcp.
__device__ __forceinline__ float sig2(float y) {          // sigmoid(x), y = x*log2e
  return __builtin_amdgcn_rcpf(1.0f + exp2f(-y));
}
__device__ __forceinline__ float th2(float y) {           // tanh(x), y = 2x*log2e
  return 1.0f - 2.0f * __builtin_amdgcn_rcpf(exp2f(y) + 1.0f);
}

__device__ __forceinline__ void gload_lds16(const void* g, void* l) {
  __builtin_amdgcn_global_load_lds(
      (const __attribute__((address_space(1))) void*)g,
      (__attribute__((address_space(3))) void*)l, 16, 0, 0);
}

// ---------------- repack kernels ----------------
// Wp[r][k] = bf16(s_g * Wc[o][1+k]),  r = ch*4+g,  o = g*512+ch.
// s_g = log2e for i,f,o (sigmoid inputs), 2*log2e for g (tanh input).
__global__ void repack_w(const float* __restrict__ Wc, const float* __restrict__ bconv,
                         unsigned short* __restrict__ Wp, float* __restrict__ w0x,
                         float* __restrict__ bx) {
  int idx = blockIdx.x * 256 + threadIdx.x;       // 2048*512 exact
  int r = idx >> 9, k = idx & 511;
  int ch = r >> 2, g = r & 3;
  int o = g * 512 + ch;
  float s = (g == 3) ? LOG2E2 : LOG2E;
  Wp[idx] = f2bf(Wc[o * 513 + 1 + k] * s);
  if (k == 0) { w0x[r] = Wc[o * 513] * s; bx[r] = bconv[o] * s; }
}

// wppb: split-bf16 W_post table for the fused u-GEMM (NOT scaled -- linear).
__global__ void repack_wpost(const float* __restrict__ Wpost, unsigned short* __restrict__ wppb) {
  int idx = blockIdx.x * 256 + threadIdx.x;       // 16*512 = 8192 exact
  if (idx >= 16 * 512) return;
  int j = idx >> 9, c = idx & 511;
  float v = (j < 9) ? Wpost[c * 9 + j] : 0.f;
  unsigned short hi = f2bf(v);
  float lo = v - bflo((uint32_t)hi);
  wppb[idx] = hi;
  wppb[16 * 512 + idx] = f2bf(lo);
}

// ---------------- fused gates-GEMM + LSTM pointwise + u-GEMM + stencil ----------------
// R14-exact structure (verified 1761 us total): BK=64 single-buffer 48 KB,
// 8 chunks/step, 2x2 waves over 256x128, T1 XCD swizzle, stash XOR-swizzle,
// phase-2 u-GEMM with same-XCD atomics, triple-buffered u, fused 9-load stencil.
// Two epilogue-only cuts vs R14:
//  (1) exp2 weight-folding (scales folded at repack; bare exp2+rcp).
//  (2) Cst in fragment-order, LANE-FASTEST: per mi one 8B f16x4 load+store
//      per lane (512B/wave segment) vs 32 scattered 2-byte RMWs.
// [Resubmitted verbatim AGAIN: round-17's measurement was contaminated --
//  two dispatches at 30.8ms/20.6ms @ 2.4 GB/s and 3% MfmaUtil (identical code
//  ran 72 us in adjacent dispatches) = GPU preemption/throttle, not kernel
//  behavior. Decision rule: clean total <=1770 keep; >1800 healthy -> revert R14.]
__global__ __launch_bounds__(256, 2)
void lstm_step(const unsigned short* __restrict__ Wp,
               const unsigned short* __restrict__ hprev,
               unsigned short* __restrict__ hnext,
               _Float16* __restrict__ Cst,
               const float* __restrict__ w0x, const float* __restrict__ bxv,
               const float* __restrict__ xin,
               const unsigned short* __restrict__ wppb,
               const float* __restrict__ uPrev, float* __restrict__ uCur,
               float* __restrict__ uNext,
               const float* __restrict__ bpost, float* __restrict__ out, int t) {
  __shared__ unsigned short As[256 * 64];   // W tile   [row r][k], XOR-swizzled chunks (32 KB)
  __shared__ unsigned short Bs[128 * 64];   // h tile   [pos][k],   XOR-swizzled chunks (16 KB)

  const int tid = threadIdx.x;
  const int lane = tid & 63;
  const int wv = tid >> 6;
  const int wm = wv >> 1, wn = wv & 1;      // 2x2 waves over 256x128 tile
  const int q = lane >> 4, l = lane & 15;

  // T1 XCD swizzle: each XCD owns 16 contiguous pos-tiles x all 8 row-tiles.
  const int lid = blockIdx.x;               // 0..1023
  const int xcd = lid & 7;
  const int s   = lid >> 3;                 // 0..127
  const int ny  = xcd * 16 + (s & 15);      // pos-tile 0..127
  const int rx  = s >> 4;                   // row-tile 0..7
  const int r0  = rx * 256;                 // gate-row base
  const int n0  = ny * 128;                 // position base
  const int ch0 = rx * 64;

  // staging map: lds byte j*4096 + tid*16 -> row j*32 + (tid>>3), stored chunk tid&7
  const int srow = tid >> 3;
  const int lchunk = (tid & 7) ^ (srow & 7);
  const unsigned short* gA = Wp    + (size_t)(r0 + srow) * 512 + lchunk * 8;
  const unsigned short* gB = hprev + (size_t)(n0 + srow) * 512 + lchunk * 8;
  char* lA = (char*)As + wv * 1024;
  char* lB = (char*)Bs + wv * 1024;

  f32x4 acc[8][4] = {};

  // issue chunk-0 staging first, then overlap stencil + u-zeroing with its latency
#pragma unroll
  for (int j = 0; j < 8; ++j)
    gload_lds16(gA + (size_t)j * (32 * 512), lA + j * 4096);
#pragma unroll
  for (int j = 0; j < 4; ++j)
    gload_lds16(gB + (size_t)j * (32 * 512), lB + j * 4096);

  // fused 3x3 stencil for step t-1 (verified-free 9-load form)
  if (t > 0 && tid < 16) {
    int pix = lid * 16 + tid;               // 1024*16 = 16384 exact
    int b = pix >> 10, p = pix & 1023;
    int py = p >> 5, px = p & 31;
    float a = bpost[0];
#pragma unroll
    for (int dy = -1; dy <= 1; ++dy) {
      int nyy = py + dy;
      if ((unsigned)nyy > 31u) continue;
#pragma unroll
      for (int dx = -1; dx <= 1; ++dx) {
        int nx = px + dx;
        if ((unsigned)nx > 31u) continue;
        int j = (dy + 1) * 3 + (dx + 1);
        a += uPrev[j * NPOS + (b << 10) + (nyy << 5) + nx];
      }
    }
    out[((b * T_ + (t - 1)) << 10) + p] = a;
  }
  // zero u[(t+1)%3] for the NEXT step's accumulation (9*NPOS = 1024*144)
  if (tid >= 16 && tid < 160)
    uNext[lid * 144 + (tid - 16)] = 0.f;

  for (int kc = 0; kc < 512; kc += 64) {
    __syncthreads();                        // implicit vmcnt drain: chunk kc ready

#pragma unroll
    for (int kk = 0; kk < 2; ++kk) {
      short8 af[8], bf_[4];
#pragma unroll
      for (int mi = 0; mi < 8; ++mi) {
        int row = wm * 128 + mi * 16 + l;
        int sidx = row * 64 + (((kk * 4 + q) ^ (row & 7)) * 8);
        af[mi] = *(const short8*)(As + sidx);
      }
#pragma unroll
      for (int ni = 0; ni < 4; ++ni) {
        int row = wn * 64 + ni * 16 + l;
        int sidx = row * 64 + (((kk * 4 + q) ^ (row & 7)) * 8);
        bf_[ni] = *(const short8*)(Bs + sidx);
      }
#pragma unroll
      for (int mi = 0; mi < 8; ++mi)
#pragma unroll
        for (int ni = 0; ni < 4; ++ni)
          acc[mi][ni] = __builtin_amdgcn_mfma_f32_16x16x32_bf16(af[mi], bf_[ni], acc[mi][ni], 0, 0, 0);
    }
    __syncthreads();                        // reads done -> safe to overwrite

    if (kc < 448) {
      int kn = kc + 64;
#pragma unroll
      for (int j = 0; j < 8; ++j)
        gload_lds16(gA + (size_t)j * (32 * 512) + kn, lA + j * 4096);
#pragma unroll
      for (int j = 0; j < 4; ++j)
        gload_lds16(gB + (size_t)j * (32 * 512) + kn, lB + j * 4096);
    }
  }

  // ---- epilogue: lane's 4 regs of acc[mi][ni] = (i,f,o,g) for one (ch,pos) ----
  float xv[4]; int posL[4];
#pragma unroll
  for (int ni = 0; ni < 4; ++ni) {
    posL[ni] = wn * 64 + ni * 16 + l;
    int pos = n0 + posL[ni];
    int b = pos >> 10, p = pos & 1023;
    xv[ni] = xin[((b * T_ + t) << 10) + p];
  }
  // C state: fragment-order, lane-fastest (8B/lane contiguous, 512B/wave/mi)
  const size_t cB = ((size_t)(lid * 4 + wv) * 2048) + lane * 4;
#pragma unroll
  for (int mi = 0; mi < 8; ++mi) {
    int chl = wm * 32 + mi * 4 + q;                    // local ch 0..63
    int rg = r0 + wm * 128 + mi * 16 + q * 4;          // global row of reg0
    float4 w0 = *(const float4*)(w0x + rg);
    float4 bb = *(const float4*)(bxv + rg);
    f16x4 cv = *(const f16x4*)(Cst + cB + mi * 256);
#pragma unroll
    for (int ni = 0; ni < 4; ++ni) {
      f32x4 g = acc[mi][ni];
      float gi = g[0] + w0.x * xv[ni] + bb.x;          // pre-scaled by log2e
      float gf = g[1] + w0.y * xv[ni] + bb.y;
      float go = g[2] + w0.z * xv[ni] + bb.z;
      float gg = g[3] + w0.w * xv[ni] + bb.w;          // pre-scaled by 2*log2e
      float cold = (float)cv[ni];
      float cn = sig2(gf) * cold + sig2(gi) + th2(gg);
      float hn = sig2(go) + th2(cn * LOG2E2);
      cv[ni] = (_Float16)cn;
      // stash for coalesced store, chunk-XOR swizzled (verified 327K conflicts)
      As[posL[ni] * 64 + (chl ^ ((posL[ni] & 7) << 3))] = f2bf(hn);
    }
    *(f16x4*)(Cst + cB + mi * 256) = cv;
  }
  __syncthreads();

  // h store (reads stash)
  {
    int pl = tid >> 1;                 // 0..127 local pos
    int cb2 = (tid & 1) << 2;          // chunk base: 0 or 4 (8-short chunks)
    const unsigned short* srcrow = As + pl * 64;
    unsigned short* dst = hnext + (size_t)(n0 + pl) * 512 + ch0 + (cb2 << 3);
#pragma unroll
    for (int i = 0; i < 4; ++i)
      ((uint4*)dst)[i] = *(const uint4*)(srcrow + (((cb2 + i) ^ (pl & 7)) << 3));
  }

  // ---- phase-2: uCur[j][pix] += sum_{ch in block} wpp[j][ch] * h[pos][ch] ----
  // 16x128x64 GEMM on the stash (8 MFMAs, split-bf16). The 8 rx-blocks of a
  // pixel accumulate via HW f32 atomicAdd -- same-XCD under T1, L2-resident.
  {
    const unsigned short* wb_hi = wppb;               // [16][512]
    const unsigned short* wb_lo = wppb + 16 * 512;
    const int posg = wv * 32;                         // wave's 32 positions
    f32x4 a2[2] = {};
#pragma unroll
    for (int kk = 0; kk < 2; ++kk) {
      const int wo = l * 512 + ch0 + kk * 32 + q * 8;
      short8 whi = *(const short8*)(wb_hi + wo);
      short8 wlo = *(const short8*)(wb_lo + wo);
#pragma unroll
      for (int ni2 = 0; ni2 < 2; ++ni2) {
        int row = posg + ni2 * 16 + l;
        int sidx = row * 64 + (((kk * 4 + q) ^ (row & 7)) * 8);
        short8 hf = *(const short8*)(As + sidx);
        a2[ni2] = __builtin_amdgcn_mfma_f32_16x16x32_bf16(whi, hf, a2[ni2], 0, 0, 0);
        a2[ni2] = __builtin_amdgcn_mfma_f32_16x16x32_bf16(wlo, hf, a2[ni2], 0, 0, 0);
      }
    }
#pragma unroll
    for (int ni2 = 0; ni2 < 2; ++ni2) {
      int pix = n0 + posg + ni2 * 16 + l;
#pragma unroll
      for (int r = 0; r < 4; ++r) {
        int j = q * 4 + r;
        if (j < 9)
          unsafeAtomicAdd(&uCur[j * NPOS + pix], a2[ni2][r]);
      }
    }
  }
}

// ---------------- 3x3 stencil over u (tail, t=T-1 only) ----------------
__global__ __launch_bounds__(256)
void conv_st(const float* __restrict__ u, const float* __restrict__ bpost,
             float* __restrict__ out, int t) {
  int idx = blockIdx.x * 256 + threadIdx.x;        // 0..16383
  int b = idx >> 10, p = idx & 1023;
  int py = p >> 5, px = p & 31;
  float acc = bpost[0];
#pragma unroll
  for (int dy = -1; dy <= 1; ++dy) {
    int ny = py + dy;
    if ((unsigned)ny > 31u) continue;
#pragma unroll
    for (int dx = -1; dx <= 1; ++dx) {
      int nx = px + dx;
      if ((unsigned)nx > 31u) continue;
      int j = (dy + 1) * 3 + (dx + 1);
      acc += u[j * NPOS + (b << 10) + (ny << 5) + nx];
    }
  }
  out[((b * T_ + t) << 10) + p] = acc;
}

// ---------------- launch ----------------
extern "C" void kernel_launch(void* const* d_in, const int* in_sizes, int n_in,
                              void* d_out, int out_size, void* d_ws, size_t ws_size,
                              hipStream_t stream) {
  const float* x     = (const float*)d_in[0];
  const float* Wconv = (const float*)d_in[1];
  const float* bconv = (const float*)d_in[2];
  const float* Wpost = (const float*)d_in[3];
  const float* bpost = (const float*)d_in[4];
  float* out = (float*)d_out;
  char* ws = (char*)d_ws;

  // workspace layout (bytes)
  unsigned short* h0   = (unsigned short*)(ws);                 // 16 MB
  unsigned short* h1   = (unsigned short*)(ws + 16777216);      // 16 MB
  _Float16*       Cst  = (_Float16*)(ws + 33554432);            // 16 MB (fp16 state, fragment-order)
  unsigned short* Wp   = (unsigned short*)(ws + 50331648);      // 2 MB
  float*          w0x  = (float*)(ws + 52428800);               // 8 KB
  float*          bx   = (float*)(ws + 52436992);               // 8 KB
  unsigned short* wppb = (unsigned short*)(ws + 52445184);      // 32 KB (split-bf16 W_post)
  float*          u0   = (float*)(ws + 52477952);               // 576 KB (9*16384 f32)
  float*          u1   = (float*)(ws + 53067776);               // 576 KB
  float*          u2   = (float*)(ws + 53657600);               // 576 KB
  float* ub[3] = {u0, u1, u2};

  hipMemsetAsync(h0, 0, 16777216, stream);
  hipMemsetAsync(Cst, 0, 16777216, stream);
  hipMemsetAsync(u0, 0, 589824, stream);
  repack_w<<<4096, 256, 0, stream>>>(Wconv, bconv, Wp, w0x, bx);
  repack_wpost<<<32, 256, 0, stream>>>(Wpost, wppb);

  unsigned short* hp = h0;
  unsigned short* hn = h1;
  for (int t = 0; t < T_; ++t) {
    const float* uPrev = ub[(t + 2) % 3];   // written by step t-1
    float*       uCur  = ub[t % 3];         // accumulated this step (pre-zeroed)
    float*       uNext = ub[(t + 1) % 3];   // zeroed this step for step t+1
    lstm_step<<<1024, 256, 0, stream>>>(Wp, hp, hn, Cst, w0x, bx, x, wppb,
                                        uPrev, uCur, uNext, bpost, out, t);
    unsigned short* tmp = hp; hp = hn; hn = tmp;
  }
  conv_st<<<64, 256, 0, stream>>>(ub[(T_ - 1) % 3], bpost, out, T_ - 1);
}

// Round 19
// 1729.687 us; speedup vs baseline: 1.2802x; 1.0474x over previous
//
#include <hip/hip_runtime.h>
#include <cstdint>
#include <cstddef>

// Problem constants
#define B_    16
#define T_    32
#define H_    512
#define P_    1024        // 32*32 spatial
#define NPOS  16384       // B_*P_
#define NG    2048        // 4*H_

typedef __attribute__((ext_vector_type(8))) short short8;
typedef __attribute__((ext_vector_type(4))) float f32x4;

__device__ __forceinline__ unsigned short f2bf(float f) {
  uint32_t u = __float_as_uint(f);
  u += 0x7fffu + ((u >> 16) & 1u);     // RNE
  return (unsigned short)(u >> 16);
}
__device__ __forceinline__ float bflo(uint32_t u) { return __uint_as_float(u << 16); }
__device__ __forceinline__ float bfhi(uint32_t u) { return __uint_as_float(u & 0xffff0000u); }

__device__ __forceinline__ float sigf(float x) {
  return __builtin_amdgcn_rcpf(1.0f + __expf(-x));
}
__device__ __forceinline__ float tanhf_(float x) {
  return 1.0f - 2.0f * __builtin_amdgcn_rcpf(__expf(2.0f * x) + 1.0f);
}

__device__ __forceinline__ void gload_lds16(const void* g, void* l) {
  __builtin_amdgcn_global_load_lds(
      (const __attribute__((address_space(1))) void*)g,
      (__attribute__((address_space(3))) void*)l, 16, 0, 0);
}

// ---------------- repack kernels ----------------
// Wp[r][k] = bf16(Wc[o][1+k]),  r = ch*4+g,  o = g*512+ch  (k-contiguous rows)
__global__ void repack_w(const float* __restrict__ Wc, const float* __restrict__ bconv,
                         unsigned short* __restrict__ Wp, float* __restrict__ w0x,
                         float* __restrict__ bx) {
  int idx = blockIdx.x * 256 + threadIdx.x;       // 2048*512 exact
  int r = idx >> 9, k = idx & 511;
  int ch = r >> 2, g = r & 3;
  int o = g * 512 + ch;
  Wp[idx] = f2bf(Wc[o * 513 + 1 + k]);
  if (k == 0) { w0x[r] = Wc[o * 513]; bx[r] = bconv[o]; }
}

// wppb: split-bf16 W_post table for the fused u-GEMM.
// wppb[0][j][c] = bf16_hi(W_post[0][c][j]), wppb[1][j][c] = bf16(val - hi).
__global__ void repack_wpost(const float* __restrict__ Wpost, unsigned short* __restrict__ wppb) {
  int idx = blockIdx.x * 256 + threadIdx.x;       // 16*512 = 8192 exact
  if (idx >= 16 * 512) return;
  int j = idx >> 9, c = idx & 511;
  float v = (j < 9) ? Wpost[c * 9 + j] : 0.f;
  unsigned short hi = f2bf(v);
  float lo = v - bflo((uint32_t)hi);
  wppb[idx] = hi;
  wppb[16 * 512 + idx] = f2bf(lo);
}

// ---------------- fused gates-GEMM + LSTM pointwise + u-GEMM + stencil ----------------
// CONSOLIDATION: verbatim revert to the session-best verified kernel
// (R14 bench: 1761.5 us total; R12 equivalent at 1763.5). The R17/R18 epilogue
// edits (exp2-folding + lane-fastest Cst) measured 1834/1811 on contaminated
// containers with VALUBusy UP -- pre-committed rule (>1800 twice) says revert.
// Structure: BK=64 single-buffer 48 KB, 8 chunks/step, 2x2 waves over 256x128,
// T1 XCD swizzle (FETCH 76->33 MB verified), stash XOR-swizzle (conflicts
// 4.1M->327K verified), scattered 2-byte Cst RMW (R10/R17 "coalesced" variants
// both failed), phase-2 u-GEMM on the stash (8 MFMAs, split-bf16, verified
// free) accumulating via same-XCD HW f32 atomics into triple-buffered u,
// fused 9-load stencil for step t-1 overlapped with chunk-0 staging.
__global__ __launch_bounds__(256, 2)
void lstm_step(const unsigned short* __restrict__ Wp,
               const unsigned short* __restrict__ hprev,
               unsigned short* __restrict__ hnext,
               _Float16* __restrict__ Cst,
               const float* __restrict__ w0x, const float* __restrict__ bxv,
               const float* __restrict__ xin,
               const unsigned short* __restrict__ wppb,
               const float* __restrict__ uPrev, float* __restrict__ uCur,
               float* __restrict__ uNext,
               const float* __restrict__ bpost, float* __restrict__ out, int t) {
  __shared__ unsigned short As[256 * 64];   // W tile   [row r][k], XOR-swizzled chunks (32 KB)
  __shared__ unsigned short Bs[128 * 64];   // h tile   [pos][k],   XOR-swizzled chunks (16 KB)

  const int tid = threadIdx.x;
  const int lane = tid & 63;
  const int wv = tid >> 6;
  const int wm = wv >> 1, wn = wv & 1;      // 2x2 waves over 256x128 tile
  const int q = lane >> 4, l = lane & 15;

  // T1 XCD swizzle: each XCD owns 16 contiguous pos-tiles x all 8 row-tiles.
  const int lid = blockIdx.x;               // 0..1023
  const int xcd = lid & 7;
  const int s   = lid >> 3;                 // 0..127
  const int ny  = xcd * 16 + (s & 15);      // pos-tile 0..127
  const int rx  = s >> 4;                   // row-tile 0..7
  const int r0  = rx * 256;                 // gate-row base
  const int n0  = ny * 128;                 // position base
  const int ch0 = rx * 64;

  // staging map: lds byte j*4096 + tid*16 -> row j*32 + (tid>>3), stored chunk tid&7
  const int srow = tid >> 3;
  const int lchunk = (tid & 7) ^ (srow & 7);
  const unsigned short* gA = Wp    + (size_t)(r0 + srow) * 512 + lchunk * 8;
  const unsigned short* gB = hprev + (size_t)(n0 + srow) * 512 + lchunk * 8;
  char* lA = (char*)As + wv * 1024;
  char* lB = (char*)Bs + wv * 1024;

  f32x4 acc[8][4] = {};

  // issue chunk-0 staging first, then overlap stencil + u-zeroing with its latency
#pragma unroll
  for (int j = 0; j < 8; ++j)
    gload_lds16(gA + (size_t)j * (32 * 512), lA + j * 4096);
#pragma unroll
  for (int j = 0; j < 4; ++j)
    gload_lds16(gB + (size_t)j * (32 * 512), lB + j * 4096);

  // fused 3x3 stencil for step t-1 (verified-free 9-load form)
  if (t > 0 && tid < 16) {
    int pix = lid * 16 + tid;               // 1024*16 = 16384 exact
    int b = pix >> 10, p = pix & 1023;
    int py = p >> 5, px = p & 31;
    float a = bpost[0];
#pragma unroll
    for (int dy = -1; dy <= 1; ++dy) {
      int nyy = py + dy;
      if ((unsigned)nyy > 31u) continue;
#pragma unroll
      for (int dx = -1; dx <= 1; ++dx) {
        int nx = px + dx;
        if ((unsigned)nx > 31u) continue;
        int j = (dy + 1) * 3 + (dx + 1);
        a += uPrev[j * NPOS + (b << 10) + (nyy << 5) + nx];
      }
    }
    out[((b * T_ + (t - 1)) << 10) + p] = a;
  }
  // zero u[(t+1)%3] for the NEXT step's accumulation (9*NPOS = 1024*144)
  if (tid >= 16 && tid < 160)
    uNext[lid * 144 + (tid - 16)] = 0.f;

  for (int kc = 0; kc < 512; kc += 64) {
    __syncthreads();                        // implicit vmcnt drain: chunk kc ready

#pragma unroll
    for (int kk = 0; kk < 2; ++kk) {
      short8 af[8], bf_[4];
#pragma unroll
      for (int mi = 0; mi < 8; ++mi) {
        int row = wm * 128 + mi * 16 + l;
        int sidx = row * 64 + (((kk * 4 + q) ^ (row & 7)) * 8);
        af[mi] = *(const short8*)(As + sidx);
      }
#pragma unroll
      for (int ni = 0; ni < 4; ++ni) {
        int row = wn * 64 + ni * 16 + l;
        int sidx = row * 64 + (((kk * 4 + q) ^ (row & 7)) * 8);
        bf_[ni] = *(const short8*)(Bs + sidx);
      }
#pragma unroll
      for (int mi = 0; mi < 8; ++mi)
#pragma unroll
        for (int ni = 0; ni < 4; ++ni)
          acc[mi][ni] = __builtin_amdgcn_mfma_f32_16x16x32_bf16(af[mi], bf_[ni], acc[mi][ni], 0, 0, 0);
    }
    __syncthreads();                        // reads done -> safe to overwrite

    if (kc < 448) {
      int kn = kc + 64;
#pragma unroll
      for (int j = 0; j < 8; ++j)
        gload_lds16(gA + (size_t)j * (32 * 512) + kn, lA + j * 4096);
#pragma unroll
      for (int j = 0; j < 4; ++j)
        gload_lds16(gB + (size_t)j * (32 * 512) + kn, lB + j * 4096);
    }
  }

  // ---- epilogue: lane's 4 regs of acc[mi][ni] = (i,f,o,g) for one (ch,pos) ----
  float xv[4]; int posL[4]; size_t cbase[4];
#pragma unroll
  for (int ni = 0; ni < 4; ++ni) {
    posL[ni] = wn * 64 + ni * 16 + l;
    int pos = n0 + posL[ni];
    int b = pos >> 10, p = pos & 1023;
    xv[ni] = xin[((b * T_ + t) << 10) + p];
    cbase[ni] = ((size_t)b << 19) + p;    // b*512*1024 + p
  }
#pragma unroll
  for (int mi = 0; mi < 8; ++mi) {
    int chl = wm * 32 + mi * 4 + q;                    // local ch 0..63
    int rg = r0 + wm * 128 + mi * 16 + q * 4;          // global row of reg0
    float4 w0 = *(const float4*)(w0x + rg);
    float4 bb = *(const float4*)(bxv + rg);
    int ch = ch0 + chl;
#pragma unroll
    for (int ni = 0; ni < 4; ++ni) {
      f32x4 g = acc[mi][ni];
      float gi = g[0] + w0.x * xv[ni] + bb.x;
      float gf = g[1] + w0.y * xv[ni] + bb.y;
      float go = g[2] + w0.z * xv[ni] + bb.z;
      float gg = g[3] + w0.w * xv[ni] + bb.w;
      size_t cidx = cbase[ni] + ((size_t)ch << 10);
      float cold = (float)Cst[cidx];
      float cn = sigf(gf) * cold + sigf(gi) + tanhf_(gg);
      float hn = sigf(go) + tanhf_(cn);
      Cst[cidx] = (_Float16)cn;
      // stash for coalesced store, chunk-XOR swizzled (verified 327K conflicts)
      As[posL[ni] * 64 + (chl ^ ((posL[ni] & 7) << 3))] = f2bf(hn);
    }
  }
  __syncthreads();

  // h store (reads stash)
  {
    int pl = tid >> 1;                 // 0..127 local pos
    int cb2 = (tid & 1) << 2;          // chunk base: 0 or 4 (8-short chunks)
    const unsigned short* srcrow = As + pl * 64;
    unsigned short* dst = hnext + (size_t)(n0 + pl) * 512 + ch0 + (cb2 << 3);
#pragma unroll
    for (int i = 0; i < 4; ++i)
      ((uint4*)dst)[i] = *(const uint4*)(srcrow + (((cb2 + i) ^ (pl & 7)) << 3));
  }

  // ---- phase-2: uCur[j][pix] += sum_{ch in block} wpp[j][ch] * h[pos][ch] ----
  // 16x128x64 GEMM on the stash (8 MFMAs, split-bf16). The 8 rx-blocks of a
  // pixel accumulate via HW f32 atomicAdd -- same-XCD under T1, L2-resident.
  {
    const unsigned short* wb_hi = wppb;               // [16][512]
    const unsigned short* wb_lo = wppb + 16 * 512;
    const int posg = wv * 32;                         // wave's 32 positions
    f32x4 a2[2] = {};
#pragma unroll
    for (int kk = 0; kk < 2; ++kk) {
      const int wo = l * 512 + ch0 + kk * 32 + q * 8;
      short8 whi = *(const short8*)(wb_hi + wo);
      short8 wlo = *(const short8*)(wb_lo + wo);
#pragma unroll
      for (int ni2 = 0; ni2 < 2; ++ni2) {
        int row = posg + ni2 * 16 + l;
        int sidx = row * 64 + (((kk * 4 + q) ^ (row & 7)) * 8);
        short8 hf = *(const short8*)(As + sidx);
        a2[ni2] = __builtin_amdgcn_mfma_f32_16x16x32_bf16(whi, hf, a2[ni2], 0, 0, 0);
        a2[ni2] = __builtin_amdgcn_mfma_f32_16x16x32_bf16(wlo, hf, a2[ni2], 0, 0, 0);
      }
    }
#pragma unroll
    for (int ni2 = 0; ni2 < 2; ++ni2) {
      int pix = n0 + posg + ni2 * 16 + l;
#pragma unroll
      for (int r = 0; r < 4; ++r) {
        int j = q * 4 + r;
        if (j < 9)
          unsafeAtomicAdd(&uCur[j * NPOS + pix], a2[ni2][r]);
      }
    }
  }
}

// ---------------- 3x3 stencil over u (tail, t=T-1 only) ----------------
__global__ __launch_bounds__(256)
void conv_st(const float* __restrict__ u, const float* __restrict__ bpost,
             float* __restrict__ out, int t) {
  int idx = blockIdx.x * 256 + threadIdx.x;        // 0..16383
  int b = idx >> 10, p = idx & 1023;
  int py = p >> 5, px = p & 31;
  float acc = bpost[0];
#pragma unroll
  for (int dy = -1; dy <= 1; ++dy) {
    int ny = py + dy;
    if ((unsigned)ny > 31u) continue;
#pragma unroll
    for (int dx = -1; dx <= 1; ++dx) {
      int nx = px + dx;
      if ((unsigned)nx > 31u) continue;
      int j = (dy + 1) * 3 + (dx + 1);
      acc += u[j * NPOS + (b << 10) + (ny << 5) + nx];
    }
  }
  out[((b * T_ + t) << 10) + p] = acc;
}

// ---------------- launch ----------------
extern "C" void kernel_launch(void* const* d_in, const int* in_sizes, int n_in,
                              void* d_out, int out_size, void* d_ws, size_t ws_size,
                              hipStream_t stream) {
  const float* x     = (const float*)d_in[0];
  const float* Wconv = (const float*)d_in[1];
  const float* bconv = (const float*)d_in[2];
  const float* Wpost = (const float*)d_in[3];
  const float* bpost = (const float*)d_in[4];
  float* out = (float*)d_out;
  char* ws = (char*)d_ws;

  // workspace layout (bytes)
  unsigned short* h0   = (unsigned short*)(ws);                 // 16 MB
  unsigned short* h1   = (unsigned short*)(ws + 16777216);      // 16 MB
  _Float16*       Cst  = (_Float16*)(ws + 33554432);            // 16 MB (fp16 state)
  unsigned short* Wp   = (unsigned short*)(ws + 50331648);      // 2 MB
  float*          w0x  = (float*)(ws + 52428800);               // 8 KB
  float*          bx   = (float*)(ws + 52436992);               // 8 KB
  unsigned short* wppb = (unsigned short*)(ws + 52445184);      // 32 KB (split-bf16 W_post)
  float*          u0   = (float*)(ws + 52477952);               // 576 KB (9*16384 f32)
  float*          u1   = (float*)(ws + 53067776);               // 576 KB
  float*          u2   = (float*)(ws + 53657600);               // 576 KB
  float* ub[3] = {u0, u1, u2};

  hipMemsetAsync(h0, 0, 16777216, stream);
  hipMemsetAsync(Cst, 0, 16777216, stream);
  hipMemsetAsync(u0, 0, 589824, stream);
  repack_w<<<4096, 256, 0, stream>>>(Wconv, bconv, Wp, w0x, bx);
  repack_wpost<<<32, 256, 0, stream>>>(Wpost, wppb);

  unsigned short* hp = h0;
  unsigned short* hn = h1;
  for (int t = 0; t < T_; ++t) {
    const float* uPrev = ub[(t + 2) % 3];   // written by step t-1
    float*       uCur  = ub[t % 3];         // accumulated this step (pre-zeroed)
    float*       uNext = ub[(t + 1) % 3];   // zeroed this step for step t+1
    lstm_step<<<1024, 256, 0, stream>>>(Wp, hp, hn, Cst, w0x, bx, x, wppb,
                                        uPrev, uCur, uNext, bpost, out, t);
    unsigned short* tmp = hp; hp = hn; hn = tmp;
  }
  conv_st<<<64, 256, 0, stream>>>(ub[(T_ - 1) % 3], bpost, out, T_ - 1);
}